// Round 9
// baseline (2023.614 us; speedup 1.0000x reference)
//
#include <hip/hip_runtime.h>

typedef unsigned short u16;
typedef unsigned int   u32;
typedef __attribute__((ext_vector_type(8))) short  short8;
typedef __attribute__((ext_vector_type(8))) unsigned short ushort8;
typedef __attribute__((ext_vector_type(4))) float  f32x4;

#define NT 1024      // timesteps
#define NN 33        // nodes
#define NE 97        // edges

__device__ __forceinline__ float b2f(u16 u){ return __uint_as_float(((u32)u)<<16); }
__device__ __forceinline__ u16 f2b(float f){
    u32 x = __float_as_uint(f);
    return (u16)((x + 0x7fffu + ((x>>16)&1u)) >> 16);
}
__device__ __forceinline__ float sigm(float x){ return 1.f/(1.f+__expf(-x)); }
__device__ __forceinline__ float tanh_(float x){ float e=__expf(2.f*x); return 1.f - 2.f/(e+1.f); }

// ---------------------------------------------------------------------------
// dtype detection: flag 0=bf16 inputs, 1=fp32 inputs.
// ---------------------------------------------------------------------------
__global__ void detect_kernel(const u32* g1_wl_raw, int* flag){
    if (threadIdx.x==0 && blockIdx.x==0){
        int hits=0;
        for (int k=0;k<256;k++){
            u32 w = g1_wl_raw[k];
            u32 e = (w>>7)&0xffu;
            if (e>=96u && e<=126u) hits++;
        }
        *flag = (hits>=160) ? 0 : 1;
    }
}

struct ConvArgs { const void* src[22]; int n[22]; int off[22]; };
__global__ void convert_kernel(ConvArgs a, const int* flag, u16* blob){
    bool isf32 = (*flag)!=0;
    int stride = gridDim.x*blockDim.x;
    for (int s=0;s<22;s++){
        int n=a.n[s]; const void* sp=a.src[s]; u16* dp=blob+a.off[s];
        for (int i=blockIdx.x*blockDim.x+threadIdx.x; i<n; i+=stride)
            dp[i] = isf32 ? f2b(((const float*)sp)[i]) : ((const u16*)sp)[i];
    }
}

// canonical blob element offsets
#define CX      0
#define CEA     67584
#define CG1WL   67880
#define CG1WR   68904
#define CG1WE   69928
#define CG1ATT  71464
#define CG1B    71976
#define CG2WL   72488
#define CG2WR   334632
#define CG2WE   596776
#define CG2ATT  598312
#define CG2B    598824
#define CL1WIH  599336
#define CL1WHH  9250088
#define CL1BIH  9315624
#define CL1BHH  9316136
#define CL2WIH  9316648
#define CL2WHH  9349416
#define CL2BIH  9365800
#define CL2BHH  9366056
#define CFCW    9366312
#define CFCB    9366568

// ---------------------------------------------------------------------------
// setup: CSR by dst + ep1/ep2 edge projections.
// ---------------------------------------------------------------------------
__global__ void setup_kernel(const int* ei, const u16* ea,
                             const u16* g1_we, const u16* g2_we,
                             int* csr, float* ep1, float* ep2)
{
    int tid = threadIdx.x;
    if (tid == 0) {
        int cnt[NN]; for (int n=0;n<NN;n++) cnt[n]=0;
        for (int e=0;e<NE;e++) cnt[ei[NE+e]]++;
        int off=0;
        for (int n=0;n<NN;n++){ csr[n]=off; off+=cnt[n]; }
        csr[NN]=off;
        int pos[NN]; for (int n=0;n<NN;n++) pos[n]=csr[n];
        for (int e=0;e<NE;e++){ int d=ei[NE+e]; csr[34+pos[d]]=e; pos[d]++; }
        for (int e=0;e<NE;e++){ csr[131+e]=ei[e]; csr[228+e]=ei[NE+e]; }
    }
    for (int i=tid; i<NE*512; i+=blockDim.x) {
        int e = i>>9, hc = i&511;
        float a0=b2f(ea[e*3]), a1=b2f(ea[e*3+1]), a2=b2f(ea[e*3+2]);
        ep1[i] = a0*b2f(g1_we[hc]) + a1*b2f(g1_we[512+hc]) + a2*b2f(g1_we[1024+hc]);
        ep2[i] = a0*b2f(g2_we[hc]) + a1*b2f(g2_we[512+hc]) + a2*b2f(g2_we[1024+hc]);
    }
}

// wlrt = [g2_wl^T ; g2_wr^T] (1024 x 512)
__global__ void wlrt_kernel(const u16* g2_wl, const u16* g2_wr, u16* wlrt)
{
    int i = blockIdx.x*256 + threadIdx.x;     // 262144 total
    int k = i>>9, c = i&511;
    wlrt[c*512 + k]        = g2_wl[i];
    wlrt[(c+512)*512 + k]  = g2_wr[i];
}

// ---------------------------------------------------------------------------
// permute LSTM weight rows to unit-major: r' = u*4+g  (orig r = g*H + u)
// ---------------------------------------------------------------------------
__global__ void permw_kernel(const u16* w1hh, const u16* w2ih, const u16* w2hh,
                             u16* w1p, u16* w2ip, u16* w2hp)
{
    int i0 = blockIdx.x*256 + threadIdx.x;
    int stride = gridDim.x*256;
    for (int j=i0; j<65536; j+=stride){
        int r=j>>7, k=j&127, u=r>>2, g=r&3;
        w1p[j] = w1hh[(g*128+u)*128 + k];
    }
    for (int j=i0; j<32768; j+=stride){
        int r=j>>7, k=j&127, u=r>>2, g=r&3;
        w2ip[j] = w2ih[(g*64+u)*128 + k];
    }
    for (int j=i0; j<16384; j+=stride){
        int r=j>>6, k=j&63, u=r>>2, g=r&3;
        w2hp[j] = w2hh[(g*64+u)*64 + k];
    }
}

// ---------------------------------------------------------------------------
// GAT layer 1: one block per timestep.
// ---------------------------------------------------------------------------
__global__ __launch_bounds__(256) void gat1_kernel(
    const u16* x, const u16* g1_wl, const u16* g1_wr, const u16* g1_att,
    const u16* g1_b, const float* ep1, const int* csr, u16* h1)
{
    __shared__ float wl[2][512], wr[2][512], att[512], bias[512];
    __shared__ float xt[2*NN];
    __shared__ float logits[NE*8];
    __shared__ float mmax[NN*8], den[NN*8];
    __shared__ int s_off[NN+1], s_eid[NE], s_src[NE], s_dst[NE];
    int t = blockIdx.x, tid = threadIdx.x;

    for (int i=tid;i<512;i+=256){
        wl[0][i]=b2f(g1_wl[i]);      wl[1][i]=b2f(g1_wl[512+i]);
        wr[0][i]=b2f(g1_wr[i]);      wr[1][i]=b2f(g1_wr[512+i]);
        att[i]=b2f(g1_att[i]);       bias[i]=b2f(g1_b[i]);
    }
    for (int i=tid;i<2*NN;i+=256) xt[i]=b2f(x[t*(2*NN)+i]);
    if (tid<NN+1) s_off[tid]=csr[tid];
    for (int i=tid;i<NE;i+=256){ s_eid[i]=csr[34+i]; s_src[i]=csr[131+i]; s_dst[i]=csr[228+i]; }
    __syncthreads();

    for (int i=tid; i<NE*8; i+=256) {
        int e=i>>3, h=i&7;
        int s=s_src[e], d=s_dst[e];
        float xs0=xt[s*2], xs1=xt[s*2+1], xd0=xt[d*2], xd1=xt[d*2+1];
        const float* epp = ep1 + e*512 + h*64;
        float acc=0.f;
        #pragma unroll 8
        for (int c=0;c<64;c++){
            int hc=h*64+c;
            float v = xs0*wl[0][hc] + xs1*wl[1][hc]
                    + xd0*wr[0][hc] + xd1*wr[1][hc] + epp[c];
            v = v>0.f ? v : 0.2f*v;
            acc += att[hc]*v;
        }
        logits[i]=acc;
    }
    __syncthreads();
    for (int i=tid; i<NN*8; i+=256) {
        int n=i>>3, h=i&7;
        float m=-1e30f;
        for (int p=s_off[n]; p<s_off[n+1]; ++p){ float v=logits[s_eid[p]*8+h]; m=v>m?v:m; }
        float s=0.f;
        for (int p=s_off[n]; p<s_off[n+1]; ++p) s += __expf(logits[s_eid[p]*8+h]-m);
        mmax[i]=m; den[i]=s+1e-16f;
    }
    __syncthreads();
    for (int i=tid; i<NE*8; i+=256) {
        int h=i&7, d=s_dst[i>>3];
        logits[i] = __expf(logits[i]-mmax[d*8+h]) / den[d*8+h];
    }
    __syncthreads();
    for (int i=tid; i<NN*512; i+=256) {
        int n=i>>9, hc=i&511, h=hc>>6;
        float acc=0.f;
        for (int p=s_off[n]; p<s_off[n+1]; ++p){
            int e=s_eid[p]; int s=s_src[e];
            float xlv = xt[s*2]*wl[0][hc] + xt[s*2+1]*wl[1][hc];
            acc += logits[e*8+h]*xlv;
        }
        acc += bias[hc];
        acc = acc>0.f ? acc : __expf(acc)-1.f;
        h1[(size_t)(t*NN+n)*512 + hc] = f2b(acc);
    }
}

// ---------------------------------------------------------------------------
// NT GEMM: C[M,N] = A[M,K] * B[N,K]^T, bf16 in, fp32 acc. 128x128 tile.
// ---------------------------------------------------------------------------
__global__ __launch_bounds__(256) void gemm_nt(
    const u16* __restrict__ A, const u16* __restrict__ B, void* Cout,
    int M, int N, int K, int kChunk, int mode)
{
    __shared__ u16 lds_a[128*40];
    __shared__ u16 lds_b[128*40];
    const int nt = blockIdx.x, mt = blockIdx.y, kc = blockIdx.z;
    const int tid = threadIdx.x;
    const int wave = tid>>6, lane = tid&63;
    const int wm = (wave&1)*64, wn = (wave>>1)*64;
    const int l15 = lane&15, quad = lane>>4;
    const int srow = tid>>2, scol = (tid&3)*8;

    const u16* Ab = A + (size_t)mt*128*K;
    const u16* Bb = B + (size_t)nt*128*K;
    const int k0beg = kc*kChunk, k0end = k0beg + kChunk;

    f32x4 acc[4][4] = {};
    for (int k0 = k0beg; k0 < k0end; k0 += 32) {
        #pragma unroll
        for (int r = 0; r < 2; ++r) {
            int row = srow + r*64;
            *(ushort8*)&lds_a[row*40 + scol] = *(const ushort8*)&Ab[(size_t)row*K + k0 + scol];
            *(ushort8*)&lds_b[row*40 + scol] = *(const ushort8*)&Bb[(size_t)row*K + k0 + scol];
        }
        __syncthreads();
        short8 af[4], bfr[4];
        #pragma unroll
        for (int i=0;i<4;i++) af[i]  = *(const short8*)&lds_a[(wm + i*16 + l15)*40 + quad*8];
        #pragma unroll
        for (int j=0;j<4;j++) bfr[j] = *(const short8*)&lds_b[(wn + j*16 + l15)*40 + quad*8];
        #pragma unroll
        for (int i=0;i<4;i++)
            #pragma unroll
            for (int j=0;j<4;j++)
                acc[i][j] = __builtin_amdgcn_mfma_f32_16x16x32_bf16(af[i], bfr[j], acc[i][j], 0,0,0);
        __syncthreads();
    }
    if (mode == 0) {
        u16* Cb = (u16*)Cout;
        #pragma unroll
        for (int i=0;i<4;i++)
            #pragma unroll
            for (int j=0;j<4;j++)
                #pragma unroll
                for (int r=0;r<4;r++){
                    int row = mt*128 + wm + i*16 + quad*4 + r;
                    int col = nt*128 + wn + j*16 + l15;
                    Cb[(size_t)row*N + col] = f2b(acc[i][j][r]);
                }
    } else {
        float* Cb = (float*)Cout + (size_t)kc*M*N;
        #pragma unroll
        for (int i=0;i<4;i++)
            #pragma unroll
            for (int j=0;j<4;j++)
                #pragma unroll
                for (int r=0;r<4;r++){
                    int row = mt*128 + wm + i*16 + quad*4 + r;
                    int col = nt*128 + wn + j*16 + l15;
                    Cb[(size_t)row*N + col] = acc[i][j][r];
                }
    }
}

// reduce split-K partials AND permute columns to unit-major (r'=u*4+g)
__global__ void reduce8_kernel(const float* part, float* out)
{
    int i = blockIdx.x*256 + threadIdx.x;   // 524288 total: t*512+c (orig col c)
    float s=0.f;
    #pragma unroll
    for (int k=0;k<8;k++) s += part[(size_t)k*524288 + i];
    int t=i>>9, c=i&511;
    out[t*512 + ((c&127)<<2) + (c>>7)] = s;
}

// ---------------------------------------------------------------------------
// GAT layer 2 attention; writes h2 PERMUTED [n][t][c].
// ---------------------------------------------------------------------------
__global__ __launch_bounds__(256) void gat2_kernel(
    const u16* C, const u16* g2_att, const u16* g2_b, const float* ep2,
    const int* csr, u16* h2)
{
    __shared__ u16 xl[NN*512];
    __shared__ float att[512], bias[512];
    __shared__ float part[NE*8];
    __shared__ float logit[NE], alpha[NE], mm[NN], dd[NN];
    __shared__ int s_off[NN+1], s_eid[NE], s_src[NE], s_dst[NE];
    int t = blockIdx.x, tid = threadIdx.x;

    for (int i=tid;i<512;i+=256){ att[i]=b2f(g2_att[i]); bias[i]=b2f(g2_b[i]); }
    if (tid<NN+1) s_off[tid]=csr[tid];
    for (int i=tid;i<NE;i+=256){ s_eid[i]=csr[34+i]; s_src[i]=csr[131+i]; s_dst[i]=csr[228+i]; }
    for (int i=tid; i<NN*64; i+=256){
        int n=i>>6, q=i&63;
        *(ushort8*)&xl[n*512+q*8] = *(const ushort8*)&C[(size_t)(t*NN+n)*1024 + q*8];
    }
    __syncthreads();

    for (int i=tid; i<NE*8; i+=256){
        int e=i>>3, q=i&7;
        int s=s_src[e], d=s_dst[e];
        const u16* xrp = C + (size_t)(t*NN+d)*1024 + 512 + q*64;
        const float* epp = ep2 + e*512 + q*64;
        const u16* xlp = xl + s*512 + q*64;
        float acc=0.f;
        #pragma unroll 8
        for (int c=0;c<64;c++){
            float v = b2f(xlp[c]) + b2f(xrp[c]) + epp[c];
            v = v>0.f ? v : 0.2f*v;
            acc += att[q*64+c]*v;
        }
        part[i]=acc;
    }
    __syncthreads();
    for (int i=tid;i<NE;i+=256){
        float s=0.f;
        #pragma unroll
        for (int q=0;q<8;q++) s+=part[i*8+q];
        logit[i]=s;
    }
    __syncthreads();
    for (int i=tid;i<NN;i+=256){
        float m=-1e30f;
        for (int p=s_off[i];p<s_off[i+1];++p){ float v=logit[s_eid[p]]; m=v>m?v:m; }
        float s=0.f;
        for (int p=s_off[i];p<s_off[i+1];++p) s+=__expf(logit[s_eid[p]]-m);
        mm[i]=m; dd[i]=s+1e-16f;
    }
    __syncthreads();
    for (int i=tid;i<NE;i+=256) alpha[i]=__expf(logit[i]-mm[s_dst[i]])/dd[s_dst[i]];
    __syncthreads();
    for (int i=tid;i<NN*512;i+=256){
        int n=i>>9, c=i&511;
        float acc=0.f;
        for (int p=s_off[n];p<s_off[n+1];++p){ int e=s_eid[p]; acc += alpha[e]*b2f(xl[s_src[e]*512+c]); }
        acc += bias[c];
        acc = acc>0.f ? acc : __expf(acc)-1.f;
        h2[(size_t)n*524288 + (size_t)t*512 + c] = f2b(acc);
    }
}

// ---------------------------------------------------------------------------
// FUSED LSTM v4. 256 threads = 4 waves (1/SIMD, launch_bounds(256,1) gives
// 512 VGPR/wave so all weight fragments stay resident).
//  wave w: lstm1 rows w*128..+127 (8 tiles x 4 K-chunks = 32 MFMA/step)
//          lstm2-hh rows w*64..+63 (4 tiles x 2 chunks = 8 MFMA/step)
//          lstm2-ih rows w*64..+63 BATCHED over 16 steps (16 MFMA / 16 steps)
//  lstm2 lags 16 steps; h1 ring(32) + z2ih ring(16). Blended gates:
//  l15<8 -> lstm1 unit w*32+l15*4+quad; l15 in [8,12) -> lstm2 unit
//  w*16+(l15-8)*4+quad. One barrier per step (h double-buffered).
// ---------------------------------------------------------------------------
__global__ __launch_bounds__(256,1) void lstm_fused_kernel(
    const float* __restrict__ pre1p,
    const u16* __restrict__ w1p, const u16* b1ih, const u16* b1hh,
    const u16* __restrict__ w2ip, const u16* __restrict__ w2hp,
    const u16* b2ih, const u16* b2hh,
    const u16* fc_w, const u16* fc_b, const int* flag, void* outv)
{
    __shared__ __align__(16) float pre_c[32*512];    // 64 KB
    __shared__ __align__(16) u16 h1hist[32*136];
    __shared__ __align__(16) float z2ih[16*268];
    __shared__ __align__(16) u16 hb1[2][128];
    __shared__ __align__(16) u16 hb2[2][64];
    __shared__ float hf[64];
    const int tid = threadIdx.x;
    const int wave = tid>>6, lane = tid&63;
    const int l15 = lane&15, quad = lane>>4;
    const f32x4 fz = {0.f,0.f,0.f,0.f};
    const float4* p4g = (const float4*)pre1p;
    float4* c4 = (float4*)pre_c;

    // weight fragments (loop-invariant; ~224 VGPRs, resident at 1 wave/SIMD)
    short8 af1[8][4];
    #pragma unroll
    for (int i=0;i<8;i++)
        #pragma unroll
        for (int c=0;c<4;c++)
            af1[i][c] = *(const short8*)&w1p[(size_t)(wave*128 + i*16 + l15)*128 + c*32 + quad*8];
    short8 af2[4][2];
    #pragma unroll
    for (int j=0;j<4;j++)
        #pragma unroll
        for (int c=0;c<2;c++)
            af2[j][c] = *(const short8*)&w2hp[(size_t)(wave*64 + j*16 + l15)*64 + c*32 + quad*8];
    short8 af3[4][4];
    #pragma unroll
    for (int j=0;j<4;j++)
        #pragma unroll
        for (int c=0;c<4;c++)
            af3[j][c] = *(const short8*)&w2ip[(size_t)(wave*64 + j*16 + l15)*128 + c*32 + quad*8];

    // per-lane unit + biases (blended between layers)
    int uu = 0;
    float bz0=0,bz1=0,bz2=0,bz3=0;
    if (l15<8){
        uu = wave*32 + l15*4 + quad;
        bz0 = b2f(b1ih[uu])     + b2f(b1hh[uu]);
        bz1 = b2f(b1ih[128+uu]) + b2f(b1hh[128+uu]);
        bz2 = b2f(b1ih[256+uu]) + b2f(b1hh[256+uu]);
        bz3 = b2f(b1ih[384+uu]) + b2f(b1hh[384+uu]);
    } else if (l15<12){
        uu = wave*16 + (l15-8)*4 + quad;
        bz0 = b2f(b2ih[uu])     + b2f(b2hh[uu]);
        bz1 = b2f(b2ih[64+uu])  + b2f(b2hh[64+uu]);
        bz2 = b2f(b2ih[128+uu]) + b2f(b2hh[128+uu]);
        bz3 = b2f(b2ih[192+uu]) + b2f(b2hh[192+uu]);
    }
    float cst = 0.f;

    if (tid<128) hb1[1][tid]=0;
    if (tid<64){ hb2[0][tid]=0; hb2[1][tid]=0; }

    for (int k=0;k<1040;k++){
        if (k<1024 && (k&31)==0){
            #pragma unroll
            for (int j=0;j<16;j++) c4[j*256+tid] = p4g[(size_t)k*128 + j*256 + tid];
            __syncthreads();
        }
        if ((k&15)==0 && k>=16 && k<=1024){
            // batched z2ih for steps [k-16, k): col l15 = step (k-16)+l15
            int cs = k-16;
            short8 hbv[4];
            #pragma unroll
            for (int c=0;c<4;c++)
                hbv[c] = *(const short8*)&h1hist[((cs+l15)&31)*136 + c*32 + quad*8];
            f32x4 ba[4] = {fz,fz,fz,fz};
            #pragma unroll
            for (int c=0;c<4;c++)
                #pragma unroll
                for (int j=0;j<4;j++)
                    ba[j] = __builtin_amdgcn_mfma_f32_16x16x32_bf16(af3[j][c], hbv[c], ba[j], 0,0,0);
            #pragma unroll
            for (int j=0;j<4;j++)
                *(f32x4*)&z2ih[l15*268 + wave*64 + j*16 + quad*4] = ba[j];
            __syncthreads();
        }
        // per-step: lstm1 step k, lstm2 step k-16
        const u16* hp1 = hb1[(k+1)&1];
        const u16* hp2 = hb2[(k+1)&1];
        short8 b1f[4];
        #pragma unroll
        for (int c=0;c<4;c++) b1f[c] = *(const short8*)&hp1[c*32 + quad*8];
        short8 b2g[2];
        #pragma unroll
        for (int c=0;c<2;c++) b2g[c] = *(const short8*)&hp2[c*32 + quad*8];

        f32x4 acc1[8] = {fz,fz,fz,fz,fz,fz,fz,fz};
        if (k<1024){
            #pragma unroll
            for (int c=0;c<4;c++)
                #pragma unroll
                for (int i=0;i<8;i++)
                    acc1[i] = __builtin_amdgcn_mfma_f32_16x16x32_bf16(af1[i][c], b1f[c], acc1[i], 0,0,0);
        }
        f32x4 acc2[4] = {fz,fz,fz,fz};
        if (k>=16){
            #pragma unroll
            for (int c=0;c<2;c++)
                #pragma unroll
                for (int j=0;j<4;j++)
                    acc2[j] = __builtin_amdgcn_mfma_f32_16x16x32_bf16(af2[j][c], b2g[c], acc2[j], 0,0,0);
        }
        // blended gates
        float4 pf = {0.f,0.f,0.f,0.f};
        if (l15<8){
            pf = *(const float4*)&pre_c[(k&31)*512 + uu*4];
        } else if (l15<12 && k>=16){
            pf = *(const float4*)&z2ih[((k-16)&15)*268 + uu*4];
        }
        f32x4 z1s = acc1[0];
        #pragma unroll
        for (int i=1;i<8;i++) z1s = (l15==i) ? acc1[i] : z1s;
        f32x4 z2s = acc2[0];
        #pragma unroll
        for (int j=1;j<4;j++) z2s = (l15==8+j) ? acc2[j] : z2s;
        f32x4 zz = (l15<8) ? z1s : z2s;
        bool act = (l15<8) ? (k<1024) : (l15<12 && k>=16);
        if (act){
            float zi = zz[0]+pf.x+bz0;
            float zf = zz[1]+pf.y+bz1;
            float zg = zz[2]+pf.z+bz2;
            float zo = zz[3]+pf.w+bz3;
            cst = sigm(zf)*cst + sigm(zi)*tanh_(zg);
            float ho = sigm(zo)*tanh_(cst);
            u16 hv = f2b(ho);
            if (l15<8){
                hb1[k&1][uu] = hv;
                h1hist[(k&31)*136 + uu] = hv;
            } else {
                hb2[k&1][uu] = hv;
                hf[uu] = ho;
            }
        }
        __syncthreads();
    }
    if (tid<4){
        float acc = b2f(fc_b[tid]);
        #pragma unroll
        for (int j=0;j<64;j++) acc += hf[j]*b2f(fc_w[tid*64+j]);
        if (*flag) ((float*)outv)[tid] = acc;
        else       ((u16*)outv)[tid]  = f2b(acc);
    }
}

// ---------------------------------------------------------------------------
extern "C" void kernel_launch(void* const* d_in, const int* in_sizes, int n_in,
                              void* d_out, int out_size, void* d_ws, size_t ws_size,
                              hipStream_t stream) {
    const int* ei = (const int*)d_in[1];
    char* ws = (char*)d_ws;

    const size_t o_blob = 0;
    const size_t o_h    = 18733184;
    const size_t o_C    = o_h    + 34603008;
    const size_t o_wlrt = o_C    + 69206016;
    const size_t o_ep1  = o_wlrt + 1048576;
    const size_t o_ep2  = o_ep1  + 198656;
    const size_t o_csr  = o_ep2  + 198656;
    const size_t o_pre1 = o_csr  + 2048;
    const size_t o_w1p  = o_pre1 + 2097152;
    const size_t o_w2ip = o_w1p  + 131072;
    const size_t o_w2hp = o_w2ip + 65536;

    u16*   blob  = (u16*)(ws + o_blob);
    u16*   h_buf = (u16*)(ws + o_h);
    u16*   Cbuf  = (u16*)(ws + o_C);
    u16*   wlrt  = (u16*)(ws + o_wlrt);
    float* ep1   = (float*)(ws + o_ep1);
    float* ep2   = (float*)(ws + o_ep2);
    int*   csr   = (int*)(ws + o_csr);
    int*   flag  = csr + 400;
    float* pre1  = (float*)(ws + o_pre1);
    u16*   w1p   = (u16*)(ws + o_w1p);
    u16*   w2ip  = (u16*)(ws + o_w2ip);
    u16*   w2hp  = (u16*)(ws + o_w2hp);
    float* part  = (float*)(ws + o_C);

    detect_kernel<<<1,64,0,stream>>>((const u32*)d_in[3], flag);

    ConvArgs ca;
    const int blob_off[22] = {CX,CEA,CG1WL,CG1WR,CG1WE,CG1ATT,CG1B,
                              CG2WL,CG2WR,CG2WE,CG2ATT,CG2B,
                              CL1WIH,CL1WHH,CL1BIH,CL1BHH,
                              CL2WIH,CL2WHH,CL2BIH,CL2BHH,CFCW,CFCB};
    const int in_idx[22]   = {0,2,3,4,5,6,7,8,9,10,11,12,13,14,15,16,17,18,19,20,21,22};
    for (int s=0;s<22;s++){
        ca.src[s]=d_in[in_idx[s]]; ca.n[s]=in_sizes[in_idx[s]]; ca.off[s]=blob_off[s];
    }
    convert_kernel<<<2048,256,0,stream>>>(ca, flag, blob);

    setup_kernel<<<1,256,0,stream>>>(ei, blob+CEA, blob+CG1WE, blob+CG2WE, csr, ep1, ep2);
    wlrt_kernel<<<1024,256,0,stream>>>(blob+CG2WL, blob+CG2WR, wlrt);
    permw_kernel<<<64,256,0,stream>>>(blob+CL1WHH, blob+CL2WIH, blob+CL2WHH, w1p, w2ip, w2hp);
    gat1_kernel<<<NT,256,0,stream>>>(blob+CX, blob+CG1WL, blob+CG1WR, blob+CG1ATT,
                                     blob+CG1B, ep1, csr, h_buf);
    gemm_nt<<<dim3(8,264,1),256,0,stream>>>(h_buf, wlrt, Cbuf, 33792, 1024, 512, 512, 0);
    gat2_kernel<<<NT,256,0,stream>>>(Cbuf, blob+CG2ATT, blob+CG2B, ep2, csr, h_buf);
    gemm_nt<<<dim3(4,8,8),256,0,stream>>>(h_buf, blob+CL1WIH, part, 1024, 512, 16896, 2112, 1);
    reduce8_kernel<<<2048,256,0,stream>>>(part, pre1);
    lstm_fused_kernel<<<1,256,0,stream>>>(pre1,
        w1p, blob+CL1BIH, blob+CL1BHH,
        w2ip, w2hp, blob+CL2BIH, blob+CL2BHH,
        blob+CFCW, blob+CFCB, flag, d_out);
}

// Round 10
// 1350.040 us; speedup vs baseline: 1.4989x; 1.4989x over previous
//
#include <hip/hip_runtime.h>

typedef unsigned short u16;
typedef unsigned int   u32;
typedef __attribute__((ext_vector_type(8))) short  short8;
typedef __attribute__((ext_vector_type(8))) unsigned short ushort8;
typedef __attribute__((ext_vector_type(4))) float  f32x4;

#define NT 1024      // timesteps
#define NN 33        // nodes
#define NE 97        // edges

__device__ __forceinline__ float b2f(u16 u){ return __uint_as_float(((u32)u)<<16); }
__device__ __forceinline__ u16 f2b(float f){
    u32 x = __float_as_uint(f);
    return (u16)((x + 0x7fffu + ((x>>16)&1u)) >> 16);
}
__device__ __forceinline__ float sigm(float x){ return 1.f/(1.f+__expf(-x)); }
__device__ __forceinline__ float tanh_(float x){ float e=__expf(2.f*x); return 1.f - 2.f/(e+1.f); }

// ---------------------------------------------------------------------------
// dtype detection: flag 0=bf16 inputs, 1=fp32 inputs.
// ---------------------------------------------------------------------------
__global__ void detect_kernel(const u32* g1_wl_raw, int* flag){
    if (threadIdx.x==0 && blockIdx.x==0){
        int hits=0;
        for (int k=0;k<256;k++){
            u32 w = g1_wl_raw[k];
            u32 e = (w>>7)&0xffu;
            if (e>=96u && e<=126u) hits++;
        }
        *flag = (hits>=160) ? 0 : 1;
    }
}

struct ConvArgs { const void* src[22]; int n[22]; int off[22]; };
__global__ void convert_kernel(ConvArgs a, const int* flag, u16* blob){
    bool isf32 = (*flag)!=0;
    int stride = gridDim.x*blockDim.x;
    for (int s=0;s<22;s++){
        int n=a.n[s]; const void* sp=a.src[s]; u16* dp=blob+a.off[s];
        for (int i=blockIdx.x*blockDim.x+threadIdx.x; i<n; i+=stride)
            dp[i] = isf32 ? f2b(((const float*)sp)[i]) : ((const u16*)sp)[i];
    }
}

// canonical blob element offsets
#define CX      0
#define CEA     67584
#define CG1WL   67880
#define CG1WR   68904
#define CG1WE   69928
#define CG1ATT  71464
#define CG1B    71976
#define CG2WL   72488
#define CG2WR   334632
#define CG2WE   596776
#define CG2ATT  598312
#define CG2B    598824
#define CL1WIH  599336
#define CL1WHH  9250088
#define CL1BIH  9315624
#define CL1BHH  9316136
#define CL2WIH  9316648
#define CL2WHH  9349416
#define CL2BIH  9365800
#define CL2BHH  9366056
#define CFCW    9366312
#define CFCB    9366568

// ---------------------------------------------------------------------------
// setup: CSR by dst + ep1/ep2 edge projections.
// ---------------------------------------------------------------------------
__global__ void setup_kernel(const int* ei, const u16* ea,
                             const u16* g1_we, const u16* g2_we,
                             int* csr, float* ep1, float* ep2)
{
    int tid = threadIdx.x;
    if (tid == 0) {
        int cnt[NN]; for (int n=0;n<NN;n++) cnt[n]=0;
        for (int e=0;e<NE;e++) cnt[ei[NE+e]]++;
        int off=0;
        for (int n=0;n<NN;n++){ csr[n]=off; off+=cnt[n]; }
        csr[NN]=off;
        int pos[NN]; for (int n=0;n<NN;n++) pos[n]=csr[n];
        for (int e=0;e<NE;e++){ int d=ei[NE+e]; csr[34+pos[d]]=e; pos[d]++; }
        for (int e=0;e<NE;e++){ csr[131+e]=ei[e]; csr[228+e]=ei[NE+e]; }
    }
    for (int i=tid; i<NE*512; i+=blockDim.x) {
        int e = i>>9, hc = i&511;
        float a0=b2f(ea[e*3]), a1=b2f(ea[e*3+1]), a2=b2f(ea[e*3+2]);
        ep1[i] = a0*b2f(g1_we[hc]) + a1*b2f(g1_we[512+hc]) + a2*b2f(g1_we[1024+hc]);
        ep2[i] = a0*b2f(g2_we[hc]) + a1*b2f(g2_we[512+hc]) + a2*b2f(g2_we[1024+hc]);
    }
}

// wlrt = [g2_wl^T ; g2_wr^T] (1024 x 512)
__global__ void wlrt_kernel(const u16* g2_wl, const u16* g2_wr, u16* wlrt)
{
    int i = blockIdx.x*256 + threadIdx.x;     // 262144 total
    int k = i>>9, c = i&511;
    wlrt[c*512 + k]        = g2_wl[i];
    wlrt[(c+512)*512 + k]  = g2_wr[i];
}

// ---------------------------------------------------------------------------
// permute LSTM weight rows to unit-major: r' = u*4+g  (orig r = g*H + u)
// ---------------------------------------------------------------------------
__global__ void permw_kernel(const u16* w1hh, const u16* w2ih, const u16* w2hh,
                             u16* w1p, u16* w2ip, u16* w2hp)
{
    int i0 = blockIdx.x*256 + threadIdx.x;
    int stride = gridDim.x*256;
    for (int j=i0; j<65536; j+=stride){
        int r=j>>7, k=j&127, u=r>>2, g=r&3;
        w1p[j] = w1hh[(g*128+u)*128 + k];
    }
    for (int j=i0; j<32768; j+=stride){
        int r=j>>7, k=j&127, u=r>>2, g=r&3;
        w2ip[j] = w2ih[(g*64+u)*128 + k];
    }
    for (int j=i0; j<16384; j+=stride){
        int r=j>>6, k=j&63, u=r>>2, g=r&3;
        w2hp[j] = w2hh[(g*64+u)*64 + k];
    }
}

// ---------------------------------------------------------------------------
// GAT layer 1: one block per timestep.
// ---------------------------------------------------------------------------
__global__ __launch_bounds__(256) void gat1_kernel(
    const u16* x, const u16* g1_wl, const u16* g1_wr, const u16* g1_att,
    const u16* g1_b, const float* ep1, const int* csr, u16* h1)
{
    __shared__ float wl[2][512], wr[2][512], att[512], bias[512];
    __shared__ float xt[2*NN];
    __shared__ float logits[NE*8];
    __shared__ float mmax[NN*8], den[NN*8];
    __shared__ int s_off[NN+1], s_eid[NE], s_src[NE], s_dst[NE];
    int t = blockIdx.x, tid = threadIdx.x;

    for (int i=tid;i<512;i+=256){
        wl[0][i]=b2f(g1_wl[i]);      wl[1][i]=b2f(g1_wl[512+i]);
        wr[0][i]=b2f(g1_wr[i]);      wr[1][i]=b2f(g1_wr[512+i]);
        att[i]=b2f(g1_att[i]);       bias[i]=b2f(g1_b[i]);
    }
    for (int i=tid;i<2*NN;i+=256) xt[i]=b2f(x[t*(2*NN)+i]);
    if (tid<NN+1) s_off[tid]=csr[tid];
    for (int i=tid;i<NE;i+=256){ s_eid[i]=csr[34+i]; s_src[i]=csr[131+i]; s_dst[i]=csr[228+i]; }
    __syncthreads();

    for (int i=tid; i<NE*8; i+=256) {
        int e=i>>3, h=i&7;
        int s=s_src[e], d=s_dst[e];
        float xs0=xt[s*2], xs1=xt[s*2+1], xd0=xt[d*2], xd1=xt[d*2+1];
        const float* epp = ep1 + e*512 + h*64;
        float acc=0.f;
        #pragma unroll 8
        for (int c=0;c<64;c++){
            int hc=h*64+c;
            float v = xs0*wl[0][hc] + xs1*wl[1][hc]
                    + xd0*wr[0][hc] + xd1*wr[1][hc] + epp[c];
            v = v>0.f ? v : 0.2f*v;
            acc += att[hc]*v;
        }
        logits[i]=acc;
    }
    __syncthreads();
    for (int i=tid; i<NN*8; i+=256) {
        int n=i>>3, h=i&7;
        float m=-1e30f;
        for (int p=s_off[n]; p<s_off[n+1]; ++p){ float v=logits[s_eid[p]*8+h]; m=v>m?v:m; }
        float s=0.f;
        for (int p=s_off[n]; p<s_off[n+1]; ++p) s += __expf(logits[s_eid[p]*8+h]-m);
        mmax[i]=m; den[i]=s+1e-16f;
    }
    __syncthreads();
    for (int i=tid; i<NE*8; i+=256) {
        int h=i&7, d=s_dst[i>>3];
        logits[i] = __expf(logits[i]-mmax[d*8+h]) / den[d*8+h];
    }
    __syncthreads();
    for (int i=tid; i<NN*512; i+=256) {
        int n=i>>9, hc=i&511, h=hc>>6;
        float acc=0.f;
        for (int p=s_off[n]; p<s_off[n+1]; ++p){
            int e=s_eid[p]; int s=s_src[e];
            float xlv = xt[s*2]*wl[0][hc] + xt[s*2+1]*wl[1][hc];
            acc += logits[e*8+h]*xlv;
        }
        acc += bias[hc];
        acc = acc>0.f ? acc : __expf(acc)-1.f;
        h1[(size_t)(t*NN+n)*512 + hc] = f2b(acc);
    }
}

// ---------------------------------------------------------------------------
// NT GEMM: C[M,N] = A[M,K] * B[N,K]^T, bf16 in, fp32 acc. 128x128 tile.
// ---------------------------------------------------------------------------
__global__ __launch_bounds__(256) void gemm_nt(
    const u16* __restrict__ A, const u16* __restrict__ B, void* Cout,
    int M, int N, int K, int kChunk, int mode)
{
    __shared__ u16 lds_a[128*40];
    __shared__ u16 lds_b[128*40];
    const int nt = blockIdx.x, mt = blockIdx.y, kc = blockIdx.z;
    const int tid = threadIdx.x;
    const int wave = tid>>6, lane = tid&63;
    const int wm = (wave&1)*64, wn = (wave>>1)*64;
    const int l15 = lane&15, quad = lane>>4;
    const int srow = tid>>2, scol = (tid&3)*8;

    const u16* Ab = A + (size_t)mt*128*K;
    const u16* Bb = B + (size_t)nt*128*K;
    const int k0beg = kc*kChunk, k0end = k0beg + kChunk;

    f32x4 acc[4][4] = {};
    for (int k0 = k0beg; k0 < k0end; k0 += 32) {
        #pragma unroll
        for (int r = 0; r < 2; ++r) {
            int row = srow + r*64;
            *(ushort8*)&lds_a[row*40 + scol] = *(const ushort8*)&Ab[(size_t)row*K + k0 + scol];
            *(ushort8*)&lds_b[row*40 + scol] = *(const ushort8*)&Bb[(size_t)row*K + k0 + scol];
        }
        __syncthreads();
        short8 af[4], bfr[4];
        #pragma unroll
        for (int i=0;i<4;i++) af[i]  = *(const short8*)&lds_a[(wm + i*16 + l15)*40 + quad*8];
        #pragma unroll
        for (int j=0;j<4;j++) bfr[j] = *(const short8*)&lds_b[(wn + j*16 + l15)*40 + quad*8];
        #pragma unroll
        for (int i=0;i<4;i++)
            #pragma unroll
            for (int j=0;j<4;j++)
                acc[i][j] = __builtin_amdgcn_mfma_f32_16x16x32_bf16(af[i], bfr[j], acc[i][j], 0,0,0);
        __syncthreads();
    }
    if (mode == 0) {
        u16* Cb = (u16*)Cout;
        #pragma unroll
        for (int i=0;i<4;i++)
            #pragma unroll
            for (int j=0;j<4;j++)
                #pragma unroll
                for (int r=0;r<4;r++){
                    int row = mt*128 + wm + i*16 + quad*4 + r;
                    int col = nt*128 + wn + j*16 + l15;
                    Cb[(size_t)row*N + col] = f2b(acc[i][j][r]);
                }
    } else {
        float* Cb = (float*)Cout + (size_t)kc*M*N;
        #pragma unroll
        for (int i=0;i<4;i++)
            #pragma unroll
            for (int j=0;j<4;j++)
                #pragma unroll
                for (int r=0;r<4;r++){
                    int row = mt*128 + wm + i*16 + quad*4 + r;
                    int col = nt*128 + wn + j*16 + l15;
                    Cb[(size_t)row*N + col] = acc[i][j][r];
                }
    }
}

// reduce split-K partials AND permute columns to unit-major (r'=u*4+g)
__global__ void reduce8_kernel(const float* part, float* out)
{
    int i = blockIdx.x*256 + threadIdx.x;   // 524288 total: t*512+c (orig col c)
    float s=0.f;
    #pragma unroll
    for (int k=0;k<8;k++) s += part[(size_t)k*524288 + i];
    int t=i>>9, c=i&511;
    out[t*512 + ((c&127)<<2) + (c>>7)] = s;
}

// ---------------------------------------------------------------------------
// GAT layer 2 attention; writes h2 PERMUTED [n][t][c].
// ---------------------------------------------------------------------------
__global__ __launch_bounds__(256) void gat2_kernel(
    const u16* C, const u16* g2_att, const u16* g2_b, const float* ep2,
    const int* csr, u16* h2)
{
    __shared__ u16 xl[NN*512];
    __shared__ float att[512], bias[512];
    __shared__ float part[NE*8];
    __shared__ float logit[NE], alpha[NE], mm[NN], dd[NN];
    __shared__ int s_off[NN+1], s_eid[NE], s_src[NE], s_dst[NE];
    int t = blockIdx.x, tid = threadIdx.x;

    for (int i=tid;i<512;i+=256){ att[i]=b2f(g2_att[i]); bias[i]=b2f(g2_b[i]); }
    if (tid<NN+1) s_off[tid]=csr[tid];
    for (int i=tid;i<NE;i+=256){ s_eid[i]=csr[34+i]; s_src[i]=csr[131+i]; s_dst[i]=csr[228+i]; }
    for (int i=tid; i<NN*64; i+=256){
        int n=i>>6, q=i&63;
        *(ushort8*)&xl[n*512+q*8] = *(const ushort8*)&C[(size_t)(t*NN+n)*1024 + q*8];
    }
    __syncthreads();

    for (int i=tid; i<NE*8; i+=256){
        int e=i>>3, q=i&7;
        int s=s_src[e], d=s_dst[e];
        const u16* xrp = C + (size_t)(t*NN+d)*1024 + 512 + q*64;
        const float* epp = ep2 + e*512 + q*64;
        const u16* xlp = xl + s*512 + q*64;
        float acc=0.f;
        #pragma unroll 8
        for (int c=0;c<64;c++){
            float v = b2f(xlp[c]) + b2f(xrp[c]) + epp[c];
            v = v>0.f ? v : 0.2f*v;
            acc += att[q*64+c]*v;
        }
        part[i]=acc;
    }
    __syncthreads();
    for (int i=tid;i<NE;i+=256){
        float s=0.f;
        #pragma unroll
        for (int q=0;q<8;q++) s+=part[i*8+q];
        logit[i]=s;
    }
    __syncthreads();
    for (int i=tid;i<NN;i+=256){
        float m=-1e30f;
        for (int p=s_off[i];p<s_off[i+1];++p){ float v=logit[s_eid[p]]; m=v>m?v:m; }
        float s=0.f;
        for (int p=s_off[i];p<s_off[i+1];++p) s+=__expf(logit[s_eid[p]]-m);
        mm[i]=m; dd[i]=s+1e-16f;
    }
    __syncthreads();
    for (int i=tid;i<NE;i+=256) alpha[i]=__expf(logit[i]-mm[s_dst[i]])/dd[s_dst[i]];
    __syncthreads();
    for (int i=tid;i<NN*512;i+=256){
        int n=i>>9, c=i&511;
        float acc=0.f;
        for (int p=s_off[n];p<s_off[n+1];++p){ int e=s_eid[p]; acc += alpha[e]*b2f(xl[s_src[e]*512+c]); }
        acc += bias[c];
        acc = acc>0.f ? acc : __expf(acc)-1.f;
        h2[(size_t)n*524288 + (size_t)t*512 + c] = f2b(acc);
    }
}

// ---------------------------------------------------------------------------
// FUSED LSTM v5: 2-block pipeline across 2 CUs (one-directional, deadlock-free
// even if serialized: consumer only waits on flags producer always sets).
//  Block 0 (512 thr, 8 waves): lstm1 only. 64 rows/wave = 4 tiles x 4 chunks
//   = 16 MFMA/wave/step (128/CU ~ 620 cyc issue, 2 waves/SIMD hides latency).
//   Every 16 steps: publish h1 chunk (16x128 bf16 = 1024 u32) to global ring
//   via agent-scope relaxed atomic stores + __syncthreads + release flag.
//  Block 1: lstm2. Acquire chunk c; batched z2ih = W2ih @ h1chunk (full 16
//   B-cols = steps); then 16 serial hh steps (rows 32/wave: 2 tiles x 2
//   chunks = 4 MFMA/wave/step) + gates; finally FC -> out.
// ---------------------------------------------------------------------------
__global__ __launch_bounds__(512) void lstm_fused_kernel(
    const float* __restrict__ pre1p,
    const u16* __restrict__ w1p, const u16* b1ih, const u16* b1hh,
    const u16* __restrict__ w2ip, const u16* __restrict__ w2hp,
    const u16* b2ih, const u16* b2hh,
    const u16* fc_w, const u16* fc_b, const int* flag,
    u32* ring, u32* flags, void* outv)
{
    const int tid = threadIdx.x;
    const int wave = tid>>6, lane = tid&63;
    const int l15 = lane&15, quad = lane>>4;
    const f32x4 fz = {0.f,0.f,0.f,0.f};

    if (blockIdx.x == 0) {
        // ================= producer: lstm1 =================
        __shared__ __align__(16) float pre_c[32*512];   // 64 KB
        __shared__ __align__(16) u16 hb1[2][128];
        __shared__ __align__(16) u16 hchunk[16*128];    // 4 KB
        const float4* p4g = (const float4*)pre1p;
        float4* c4 = (float4*)pre_c;
        u32* hc32 = (u32*)hchunk;

        short8 af1[4][4];
        #pragma unroll
        for (int i=0;i<4;i++)
            #pragma unroll
            for (int c=0;c<4;c++)
                af1[i][c] = *(const short8*)&w1p[(size_t)(wave*64 + i*16 + l15)*128 + c*32 + quad*8];

        int uu = 0; float bz0=0,bz1=0,bz2=0,bz3=0;
        if (l15<4){
            uu = wave*16 + l15*4 + quad;
            bz0 = b2f(b1ih[uu])     + b2f(b1hh[uu]);
            bz1 = b2f(b1ih[128+uu]) + b2f(b1hh[128+uu]);
            bz2 = b2f(b1ih[256+uu]) + b2f(b1hh[256+uu]);
            bz3 = b2f(b1ih[384+uu]) + b2f(b1hh[384+uu]);
        }
        float cst = 0.f;
        if (tid<128) hb1[1][tid]=0;

        for (int k=0;k<=1024;k++){
            if (k>=16 && (k&15)==0){
                // publish chunk c = k/16 - 1 (data written before last barrier)
                int c = (k>>4) - 1;
                u32* dst = ring + c*1024;
                __hip_atomic_store(&dst[tid],     hc32[tid],     __ATOMIC_RELAXED, __HIP_MEMORY_SCOPE_AGENT);
                __hip_atomic_store(&dst[tid+512], hc32[tid+512], __ATOMIC_RELAXED, __HIP_MEMORY_SCOPE_AGENT);
                __syncthreads();   // drains vmcnt -> all data stores complete
                if (tid==0)
                    __hip_atomic_store(&flags[c], (u32)(c+1), __ATOMIC_RELEASE, __HIP_MEMORY_SCOPE_AGENT);
            }
            if (k<1024 && (k&31)==0){
                #pragma unroll
                for (int j=0;j<8;j++) c4[j*512+tid] = p4g[(size_t)k*128 + j*512 + tid];
                __syncthreads();
            }
            if (k<1024){
                const u16* hp = hb1[(k+1)&1];
                short8 b0 = *(const short8*)&hp[quad*8];
                short8 b1 = *(const short8*)&hp[32+quad*8];
                short8 b2 = *(const short8*)&hp[64+quad*8];
                short8 b3 = *(const short8*)&hp[96+quad*8];
                f32x4 acc[4];
                #pragma unroll
                for (int i=0;i<4;i++){
                    f32x4 a = __builtin_amdgcn_mfma_f32_16x16x32_bf16(af1[i][0], b0, fz, 0,0,0);
                    a = __builtin_amdgcn_mfma_f32_16x16x32_bf16(af1[i][1], b1, a, 0,0,0);
                    a = __builtin_amdgcn_mfma_f32_16x16x32_bf16(af1[i][2], b2, a, 0,0,0);
                    a = __builtin_amdgcn_mfma_f32_16x16x32_bf16(af1[i][3], b3, a, 0,0,0);
                    acc[i] = a;
                }
                f32x4 z = acc[0];
                #pragma unroll
                for (int i=1;i<4;i++) z = (l15==i) ? acc[i] : z;
                if (l15<4){
                    const float4 pf = *(const float4*)&pre_c[(k&31)*512 + uu*4];
                    float zi = z[0]+pf.x+bz0;
                    float zf = z[1]+pf.y+bz1;
                    float zg = z[2]+pf.z+bz2;
                    float zo = z[3]+pf.w+bz3;
                    cst = sigm(zf)*cst + sigm(zi)*tanh_(zg);
                    float ho = sigm(zo)*tanh_(cst);
                    u16 hv = f2b(ho);
                    hb1[k&1][uu] = hv;
                    hchunk[(k&15)*128 + uu] = hv;
                }
            }
            __syncthreads();
        }
    } else {
        // ================= consumer: lstm2 + FC =================
        __shared__ __align__(16) u16 h1c[16*136];       // padded rows (136)
        __shared__ __align__(16) float z2l[16*264];     // padded rows (264)
        __shared__ __align__(16) u16 hb2[2][64];
        __shared__ float hf[64];

        short8 af2[2][2];
        #pragma unroll
        for (int j=0;j<2;j++)
            #pragma unroll
            for (int c=0;c<2;c++)
                af2[j][c] = *(const short8*)&w2hp[(size_t)(wave*32 + j*16 + l15)*64 + c*32 + quad*8];
        short8 af3[2][4];
        #pragma unroll
        for (int j=0;j<2;j++)
            #pragma unroll
            for (int c=0;c<4;c++)
                af3[j][c] = *(const short8*)&w2ip[(size_t)(wave*32 + j*16 + l15)*128 + c*32 + quad*8];

        int u2 = 0; float bz0=0,bz1=0,bz2=0,bz3=0;
        if (l15<2){
            u2 = wave*8 + l15*4 + quad;
            bz0 = b2f(b2ih[u2])     + b2f(b2hh[u2]);
            bz1 = b2f(b2ih[64+u2])  + b2f(b2hh[64+u2]);
            bz2 = b2f(b2ih[128+u2]) + b2f(b2hh[128+u2]);
            bz3 = b2f(b2ih[192+u2]) + b2f(b2hh[192+u2]);
        }
        float cst = 0.f;
        if (tid<64) hb2[1][tid]=0;
        __syncthreads();

        u32* h1c32 = (u32*)h1c;
        for (int c=0;c<64;c++){
            if (tid==0){
                while (__hip_atomic_load(&flags[c], __ATOMIC_ACQUIRE, __HIP_MEMORY_SCOPE_AGENT) != (u32)(c+1))
                    __builtin_amdgcn_s_sleep(2);
            }
            __syncthreads();
            // load chunk (1024 u32) into padded LDS rows (68 u32/row)
            const u32* src = ring + c*1024;
            #pragma unroll
            for (int j=0;j<2;j++){
                int i = tid + j*512;
                u32 v = __hip_atomic_load(&src[i], __ATOMIC_RELAXED, __HIP_MEMORY_SCOPE_AGENT);
                int s = i>>6, w2 = i&63;
                h1c32[s*68 + w2] = v;
            }
            __syncthreads();
            // batched z2ih: col l15 = step within chunk
            short8 hbv[4];
            #pragma unroll
            for (int cc=0;cc<4;cc++)
                hbv[cc] = *(const short8*)&h1c[l15*136 + cc*32 + quad*8];
            f32x4 ba[2] = {fz,fz};
            #pragma unroll
            for (int cc=0;cc<4;cc++){
                ba[0] = __builtin_amdgcn_mfma_f32_16x16x32_bf16(af3[0][cc], hbv[cc], ba[0], 0,0,0);
                ba[1] = __builtin_amdgcn_mfma_f32_16x16x32_bf16(af3[1][cc], hbv[cc], ba[1], 0,0,0);
            }
            *(f32x4*)&z2l[l15*264 + (wave*8 + quad)*4]     = ba[0];
            *(f32x4*)&z2l[l15*264 + (wave*8 + 4 + quad)*4] = ba[1];
            __syncthreads();
            // 16 serial steps
            for (int s=0;s<16;s++){
                int sg = c*16 + s;
                const u16* hp2 = hb2[(sg+1)&1];
                short8 g0 = *(const short8*)&hp2[quad*8];
                short8 g1 = *(const short8*)&hp2[32+quad*8];
                f32x4 a0 = __builtin_amdgcn_mfma_f32_16x16x32_bf16(af2[0][0], g0, fz, 0,0,0);
                a0 = __builtin_amdgcn_mfma_f32_16x16x32_bf16(af2[0][1], g1, a0, 0,0,0);
                f32x4 a1 = __builtin_amdgcn_mfma_f32_16x16x32_bf16(af2[1][0], g0, fz, 0,0,0);
                a1 = __builtin_amdgcn_mfma_f32_16x16x32_bf16(af2[1][1], g1, a1, 0,0,0);
                f32x4 z = (l15==1) ? a1 : a0;
                if (l15<2){
                    const float4 pf = *(const float4*)&z2l[s*264 + u2*4];
                    float zi = z[0]+pf.x+bz0;
                    float zf = z[1]+pf.y+bz1;
                    float zg = z[2]+pf.z+bz2;
                    float zo = z[3]+pf.w+bz3;
                    cst = sigm(zf)*cst + sigm(zi)*tanh_(zg);
                    float ho = sigm(zo)*tanh_(cst);
                    hb2[sg&1][u2] = f2b(ho);
                    hf[u2] = ho;
                }
                __syncthreads();
            }
        }
        if (tid<4){
            float acc = b2f(fc_b[tid]);
            #pragma unroll
            for (int j=0;j<64;j++) acc += hf[j]*b2f(fc_w[tid*64+j]);
            if (*flag) ((float*)outv)[tid] = acc;
            else       ((u16*)outv)[tid]  = f2b(acc);
        }
    }
}

// ---------------------------------------------------------------------------
extern "C" void kernel_launch(void* const* d_in, const int* in_sizes, int n_in,
                              void* d_out, int out_size, void* d_ws, size_t ws_size,
                              hipStream_t stream) {
    const int* ei = (const int*)d_in[1];
    char* ws = (char*)d_ws;

    const size_t o_blob = 0;
    const size_t o_h    = 18733184;
    const size_t o_C    = o_h    + 34603008;
    const size_t o_wlrt = o_C    + 69206016;
    const size_t o_ep1  = o_wlrt + 1048576;
    const size_t o_ep2  = o_ep1  + 198656;
    const size_t o_csr  = o_ep2  + 198656;
    const size_t o_pre1 = o_csr  + 2048;
    const size_t o_w1p  = o_pre1 + 2097152;
    const size_t o_w2ip = o_w1p  + 131072;
    const size_t o_w2hp = o_w2ip + 65536;
    const size_t o_ring = o_w2hp + 32768;     // 64 chunks x 4096 B = 262144
    const size_t o_flgs = o_ring + 262144;    // 256 B

    u16*   blob  = (u16*)(ws + o_blob);
    u16*   h_buf = (u16*)(ws + o_h);
    u16*   Cbuf  = (u16*)(ws + o_C);
    u16*   wlrt  = (u16*)(ws + o_wlrt);
    float* ep1   = (float*)(ws + o_ep1);
    float* ep2   = (float*)(ws + o_ep2);
    int*   csr   = (int*)(ws + o_csr);
    int*   flag  = csr + 400;
    float* pre1  = (float*)(ws + o_pre1);
    u16*   w1p   = (u16*)(ws + o_w1p);
    u16*   w2ip  = (u16*)(ws + o_w2ip);
    u16*   w2hp  = (u16*)(ws + o_w2hp);
    u32*   ring  = (u32*)(ws + o_ring);
    u32*   flags = (u32*)(ws + o_flgs);
    float* part  = (float*)(ws + o_C);

    detect_kernel<<<1,64,0,stream>>>((const u32*)d_in[3], flag);

    ConvArgs ca;
    const int blob_off[22] = {CX,CEA,CG1WL,CG1WR,CG1WE,CG1ATT,CG1B,
                              CG2WL,CG2WR,CG2WE,CG2ATT,CG2B,
                              CL1WIH,CL1WHH,CL1BIH,CL1BHH,
                              CL2WIH,CL2WHH,CL2BIH,CL2BHH,CFCW,CFCB};
    const int in_idx[22]   = {0,2,3,4,5,6,7,8,9,10,11,12,13,14,15,16,17,18,19,20,21,22};
    for (int s=0;s<22;s++){
        ca.src[s]=d_in[in_idx[s]]; ca.n[s]=in_sizes[in_idx[s]]; ca.off[s]=blob_off[s];
    }
    convert_kernel<<<2048,256,0,stream>>>(ca, flag, blob);

    setup_kernel<<<1,256,0,stream>>>(ei, blob+CEA, blob+CG1WE, blob+CG2WE, csr, ep1, ep2);
    wlrt_kernel<<<1024,256,0,stream>>>(blob+CG2WL, blob+CG2WR, wlrt);
    permw_kernel<<<64,256,0,stream>>>(blob+CL1WHH, blob+CL2WIH, blob+CL2WHH, w1p, w2ip, w2hp);
    gat1_kernel<<<NT,256,0,stream>>>(blob+CX, blob+CG1WL, blob+CG1WR, blob+CG1ATT,
                                     blob+CG1B, ep1, csr, h_buf);
    gemm_nt<<<dim3(8,264,1),256,0,stream>>>(h_buf, wlrt, Cbuf, 33792, 1024, 512, 512, 0);
    gat2_kernel<<<NT,256,0,stream>>>(Cbuf, blob+CG2ATT, blob+CG2B, ep2, csr, h_buf);
    gemm_nt<<<dim3(4,8,8),256,0,stream>>>(h_buf, blob+CL1WIH, part, 1024, 512, 16896, 2112, 1);
    reduce8_kernel<<<2048,256,0,stream>>>(part, pre1);
    lstm_fused_kernel<<<2,512,0,stream>>>(pre1,
        w1p, blob+CL1BIH, blob+CL1BHH,
        w2ip, w2hp, blob+CL2BIH, blob+CL2BHH,
        blob+CFCW, blob+CFCB, flag, ring, flags, d_out);
}

// Round 11
// 1340.209 us; speedup vs baseline: 1.5099x; 1.0073x over previous
//
#include <hip/hip_runtime.h>

typedef unsigned short u16;
typedef unsigned int   u32;
typedef __attribute__((ext_vector_type(8))) short  short8;
typedef __attribute__((ext_vector_type(8))) unsigned short ushort8;
typedef __attribute__((ext_vector_type(4))) float  f32x4;

#define NT 1024      // timesteps
#define NN 33        // nodes
#define NE 97        // edges

__device__ __forceinline__ float b2f(u16 u){ return __uint_as_float(((u32)u)<<16); }
__device__ __forceinline__ u16 f2b(float f){
    u32 x = __float_as_uint(f);
    return (u16)((x + 0x7fffu + ((x>>16)&1u)) >> 16);
}
__device__ __forceinline__ float sigm(float x){ return 1.f/(1.f+__expf(-x)); }
__device__ __forceinline__ float tanh_(float x){ float e=__expf(2.f*x); return 1.f - 2.f/(e+1.f); }

// ---------------------------------------------------------------------------
// convert: per-block dtype detection (deterministic, identical in all blocks),
// block 0 also publishes flag (0=bf16 inputs, 1=fp32) for the final kernel.
// ---------------------------------------------------------------------------
struct ConvArgs { const void* src[22]; int n[22]; int off[22]; };
__global__ void convert_kernel(ConvArgs a, const u32* raw, int* flag, u16* blob){
    __shared__ int s_isf32;
    if (threadIdx.x==0){
        int hits=0;
        for (int k=0;k<256;k++){
            u32 w = raw[k];
            u32 e = (w>>7)&0xffu;
            if (e>=96u && e<=126u) hits++;
        }
        s_isf32 = (hits>=160) ? 0 : 1;
        if (blockIdx.x==0) *flag = s_isf32;
    }
    __syncthreads();
    bool isf32 = s_isf32!=0;
    int stride = gridDim.x*blockDim.x;
    for (int s=0;s<22;s++){
        int n=a.n[s]; const void* sp=a.src[s]; u16* dp=blob+a.off[s];
        for (int i=blockIdx.x*blockDim.x+threadIdx.x; i<n; i+=stride)
            dp[i] = isf32 ? f2b(((const float*)sp)[i]) : ((const u16*)sp)[i];
    }
}

// canonical blob element offsets
#define CX      0
#define CEA     67584
#define CG1WL   67880
#define CG1WR   68904
#define CG1WE   69928
#define CG1ATT  71464
#define CG1B    71976
#define CG2WL   72488
#define CG2WR   334632
#define CG2WE   596776
#define CG2ATT  598312
#define CG2B    598824
#define CL1WIH  599336
#define CL1WHH  9250088
#define CL1BIH  9315624
#define CL1BHH  9316136
#define CL2WIH  9316648
#define CL2WHH  9349416
#define CL2BIH  9365800
#define CL2BHH  9366056
#define CFCW    9366312
#define CFCB    9366568

// ---------------------------------------------------------------------------
// prep (merged setup+wlrt+permw): block 0 = CSR + edge projections;
// blocks 1..1024 = wlrt transpose; blocks 1025..1088 = LSTM weight permute.
// csr ints: [0..33]=off, [34..130]=eid, [131..227]=src, [228..324]=dst
// ---------------------------------------------------------------------------
__global__ void prep_kernel(const int* ei, const u16* ea,
                            const u16* g1_we, const u16* g2_we,
                            const u16* g2_wl, const u16* g2_wr,
                            const u16* w1hh, const u16* w2ih, const u16* w2hh,
                            int* csr, float* ep1, float* ep2, u16* wlrt,
                            u16* w1p, u16* w2ip, u16* w2hp)
{
    int b = blockIdx.x, tid = threadIdx.x;
    if (b==0){
        if (tid == 0) {
            int cnt[NN]; for (int n=0;n<NN;n++) cnt[n]=0;
            for (int e=0;e<NE;e++) cnt[ei[NE+e]]++;
            int off=0;
            for (int n=0;n<NN;n++){ csr[n]=off; off+=cnt[n]; }
            csr[NN]=off;
            int pos[NN]; for (int n=0;n<NN;n++) pos[n]=csr[n];
            for (int e=0;e<NE;e++){ int d=ei[NE+e]; csr[34+pos[d]]=e; pos[d]++; }
            for (int e=0;e<NE;e++){ csr[131+e]=ei[e]; csr[228+e]=ei[NE+e]; }
        }
        for (int i=tid; i<NE*512; i+=256) {
            int e = i>>9, hc = i&511;
            float a0=b2f(ea[e*3]), a1=b2f(ea[e*3+1]), a2=b2f(ea[e*3+2]);
            ep1[i] = a0*b2f(g1_we[hc]) + a1*b2f(g1_we[512+hc]) + a2*b2f(g1_we[1024+hc]);
            ep2[i] = a0*b2f(g2_we[hc]) + a1*b2f(g2_we[512+hc]) + a2*b2f(g2_we[1024+hc]);
        }
    } else if (b<=1024){
        int i = (b-1)*256 + tid;              // 262144 total
        int k = i>>9, c = i&511;
        wlrt[c*512 + k]        = g2_wl[i];
        wlrt[(c+512)*512 + k]  = g2_wr[i];
    } else {
        int i0 = (b-1025)*256 + tid;          // 64 blocks
        int stride = 64*256;
        for (int j=i0; j<65536; j+=stride){
            int r=j>>7, k=j&127, u=r>>2, g=r&3;
            w1p[j] = w1hh[(g*128+u)*128 + k];
        }
        for (int j=i0; j<32768; j+=stride){
            int r=j>>7, k=j&127, u=r>>2, g=r&3;
            w2ip[j] = w2ih[(g*64+u)*128 + k];
        }
        for (int j=i0; j<16384; j+=stride){
            int r=j>>6, k=j&63, u=r>>2, g=r&3;
            w2hp[j] = w2hh[(g*64+u)*64 + k];
        }
    }
}

// ---------------------------------------------------------------------------
// GAT layer 1: one block per timestep.
// ---------------------------------------------------------------------------
__global__ __launch_bounds__(256) void gat1_kernel(
    const u16* x, const u16* g1_wl, const u16* g1_wr, const u16* g1_att,
    const u16* g1_b, const float* ep1, const int* csr, u16* h1)
{
    __shared__ float wl[2][512], wr[2][512], att[512], bias[512];
    __shared__ float xt[2*NN];
    __shared__ float logits[NE*8];
    __shared__ float mmax[NN*8], den[NN*8];
    __shared__ int s_off[NN+1], s_eid[NE], s_src[NE], s_dst[NE];
    int t = blockIdx.x, tid = threadIdx.x;

    for (int i=tid;i<512;i+=256){
        wl[0][i]=b2f(g1_wl[i]);      wl[1][i]=b2f(g1_wl[512+i]);
        wr[0][i]=b2f(g1_wr[i]);      wr[1][i]=b2f(g1_wr[512+i]);
        att[i]=b2f(g1_att[i]);       bias[i]=b2f(g1_b[i]);
    }
    for (int i=tid;i<2*NN;i+=256) xt[i]=b2f(x[t*(2*NN)+i]);
    if (tid<NN+1) s_off[tid]=csr[tid];
    for (int i=tid;i<NE;i+=256){ s_eid[i]=csr[34+i]; s_src[i]=csr[131+i]; s_dst[i]=csr[228+i]; }
    __syncthreads();

    for (int i=tid; i<NE*8; i+=256) {
        int e=i>>3, h=i&7;
        int s=s_src[e], d=s_dst[e];
        float xs0=xt[s*2], xs1=xt[s*2+1], xd0=xt[d*2], xd1=xt[d*2+1];
        const float* epp = ep1 + e*512 + h*64;
        float acc=0.f;
        #pragma unroll 8
        for (int c=0;c<64;c++){
            int hc=h*64+c;
            float v = xs0*wl[0][hc] + xs1*wl[1][hc]
                    + xd0*wr[0][hc] + xd1*wr[1][hc] + epp[c];
            v = v>0.f ? v : 0.2f*v;
            acc += att[hc]*v;
        }
        logits[i]=acc;
    }
    __syncthreads();
    for (int i=tid; i<NN*8; i+=256) {
        int n=i>>3, h=i&7;
        float m=-1e30f;
        for (int p=s_off[n]; p<s_off[n+1]; ++p){ float v=logits[s_eid[p]*8+h]; m=v>m?v:m; }
        float s=0.f;
        for (int p=s_off[n]; p<s_off[n+1]; ++p) s += __expf(logits[s_eid[p]*8+h]-m);
        mmax[i]=m; den[i]=s+1e-16f;
    }
    __syncthreads();
    for (int i=tid; i<NE*8; i+=256) {
        int h=i&7, d=s_dst[i>>3];
        logits[i] = __expf(logits[i]-mmax[d*8+h]) / den[d*8+h];
    }
    __syncthreads();
    for (int i=tid; i<NN*512; i+=256) {
        int n=i>>9, hc=i&511, h=hc>>6;
        float acc=0.f;
        for (int p=s_off[n]; p<s_off[n+1]; ++p){
            int e=s_eid[p]; int s=s_src[e];
            float xlv = xt[s*2]*wl[0][hc] + xt[s*2+1]*wl[1][hc];
            acc += logits[e*8+h]*xlv;
        }
        acc += bias[hc];
        acc = acc>0.f ? acc : __expf(acc)-1.f;
        h1[(size_t)(t*NN+n)*512 + hc] = f2b(acc);
    }
}

// ---------------------------------------------------------------------------
// NT GEMM: C[M,N] = A[M,K] * B[N,K]^T, bf16 in, fp32 acc. 128x128 tile.
// ---------------------------------------------------------------------------
__global__ __launch_bounds__(256) void gemm_nt(
    const u16* __restrict__ A, const u16* __restrict__ B, void* Cout,
    int M, int N, int K, int kChunk, int mode)
{
    __shared__ u16 lds_a[128*40];
    __shared__ u16 lds_b[128*40];
    const int nt = blockIdx.x, mt = blockIdx.y, kc = blockIdx.z;
    const int tid = threadIdx.x;
    const int wave = tid>>6, lane = tid&63;
    const int wm = (wave&1)*64, wn = (wave>>1)*64;
    const int l15 = lane&15, quad = lane>>4;
    const int srow = tid>>2, scol = (tid&3)*8;

    const u16* Ab = A + (size_t)mt*128*K;
    const u16* Bb = B + (size_t)nt*128*K;
    const int k0beg = kc*kChunk, k0end = k0beg + kChunk;

    f32x4 acc[4][4] = {};
    for (int k0 = k0beg; k0 < k0end; k0 += 32) {
        #pragma unroll
        for (int r = 0; r < 2; ++r) {
            int row = srow + r*64;
            *(ushort8*)&lds_a[row*40 + scol] = *(const ushort8*)&Ab[(size_t)row*K + k0 + scol];
            *(ushort8*)&lds_b[row*40 + scol] = *(const ushort8*)&Bb[(size_t)row*K + k0 + scol];
        }
        __syncthreads();
        short8 af[4], bfr[4];
        #pragma unroll
        for (int i=0;i<4;i++) af[i]  = *(const short8*)&lds_a[(wm + i*16 + l15)*40 + quad*8];
        #pragma unroll
        for (int j=0;j<4;j++) bfr[j] = *(const short8*)&lds_b[(wn + j*16 + l15)*40 + quad*8];
        #pragma unroll
        for (int i=0;i<4;i++)
            #pragma unroll
            for (int j=0;j<4;j++)
                acc[i][j] = __builtin_amdgcn_mfma_f32_16x16x32_bf16(af[i], bfr[j], acc[i][j], 0,0,0);
        __syncthreads();
    }
    if (mode == 0) {
        u16* Cb = (u16*)Cout;
        #pragma unroll
        for (int i=0;i<4;i++)
            #pragma unroll
            for (int j=0;j<4;j++)
                #pragma unroll
                for (int r=0;r<4;r++){
                    int row = mt*128 + wm + i*16 + quad*4 + r;
                    int col = nt*128 + wn + j*16 + l15;
                    Cb[(size_t)row*N + col] = f2b(acc[i][j][r]);
                }
    } else {
        float* Cb = (float*)Cout + (size_t)kc*M*N;
        #pragma unroll
        for (int i=0;i<4;i++)
            #pragma unroll
            for (int j=0;j<4;j++)
                #pragma unroll
                for (int r=0;r<4;r++){
                    int row = mt*128 + wm + i*16 + quad*4 + r;
                    int col = nt*128 + wn + j*16 + l15;
                    Cb[(size_t)row*N + col] = acc[i][j][r];
                }
    }
}

// reduce split-K partials, permute cols to unit-major (r'=u*4+g), ADD BIAS
__global__ void reduce8_kernel(const float* part, const u16* b1ih, const u16* b1bhh, float* out)
{
    int i = blockIdx.x*256 + threadIdx.x;   // 524288 total: t*512+c (orig col c)
    float s=0.f;
    #pragma unroll
    for (int k=0;k<8;k++) s += part[(size_t)k*524288 + i];
    int t=i>>9, c=i&511;
    s += b2f(b1ih[c]) + b2f(b1bhh[c]);
    out[t*512 + ((c&127)<<2) + (c>>7)] = s;
}

// ---------------------------------------------------------------------------
// GAT layer 2 attention; writes h2 PERMUTED [n][t][c].
// ---------------------------------------------------------------------------
__global__ __launch_bounds__(256) void gat2_kernel(
    const u16* C, const u16* g2_att, const u16* g2_b, const float* ep2,
    const int* csr, u16* h2)
{
    __shared__ u16 xl[NN*512];
    __shared__ float att[512], bias[512];
    __shared__ float part[NE*8];
    __shared__ float logit[NE], alpha[NE], mm[NN], dd[NN];
    __shared__ int s_off[NN+1], s_eid[NE], s_src[NE], s_dst[NE];
    int t = blockIdx.x, tid = threadIdx.x;

    for (int i=tid;i<512;i+=256){ att[i]=b2f(g2_att[i]); bias[i]=b2f(g2_b[i]); }
    if (tid<NN+1) s_off[tid]=csr[tid];
    for (int i=tid;i<NE;i+=256){ s_eid[i]=csr[34+i]; s_src[i]=csr[131+i]; s_dst[i]=csr[228+i]; }
    for (int i=tid; i<NN*64; i+=256){
        int n=i>>6, q=i&63;
        *(ushort8*)&xl[n*512+q*8] = *(const ushort8*)&C[(size_t)(t*NN+n)*1024 + q*8];
    }
    __syncthreads();

    for (int i=tid; i<NE*8; i+=256){
        int e=i>>3, q=i&7;
        int s=s_src[e], d=s_dst[e];
        const u16* xrp = C + (size_t)(t*NN+d)*1024 + 512 + q*64;
        const float* epp = ep2 + e*512 + q*64;
        const u16* xlp = xl + s*512 + q*64;
        float acc=0.f;
        #pragma unroll 8
        for (int c=0;c<64;c++){
            float v = b2f(xlp[c]) + b2f(xrp[c]) + epp[c];
            v = v>0.f ? v : 0.2f*v;
            acc += att[q*64+c]*v;
        }
        part[i]=acc;
    }
    __syncthreads();
    for (int i=tid;i<NE;i+=256){
        float s=0.f;
        #pragma unroll
        for (int q=0;q<8;q++) s+=part[i*8+q];
        logit[i]=s;
    }
    __syncthreads();
    for (int i=tid;i<NN;i+=256){
        float m=-1e30f;
        for (int p=s_off[i];p<s_off[i+1];++p){ float v=logit[s_eid[p]]; m=v>m?v:m; }
        float s=0.f;
        for (int p=s_off[i];p<s_off[i+1];++p) s+=__expf(logit[s_eid[p]]-m);
        mm[i]=m; dd[i]=s+1e-16f;
    }
    __syncthreads();
    for (int i=tid;i<NE;i+=256) alpha[i]=__expf(logit[i]-mm[s_dst[i]])/dd[s_dst[i]];
    __syncthreads();
    for (int i=tid;i<NN*512;i+=256){
        int n=i>>9, c=i&511;
        float acc=0.f;
        for (int p=s_off[n];p<s_off[n+1];++p){ int e=s_eid[p]; acc += alpha[e]*b2f(xl[s_src[e]*512+c]); }
        acc += bias[c];
        acc = acc>0.f ? acc : __expf(acc)-1.f;
        h2[(size_t)n*524288 + (size_t)t*512 + c] = f2b(acc);
    }
}

// ---------------------------------------------------------------------------
// FUSED LSTM v5.1: 2-block pipeline (R10 structure, VALU-trimmed producer).
//  Bias folded into pre1 (reduce8); hoisted LDS pointers; rolling pre_c ptr.
// ---------------------------------------------------------------------------
__global__ __launch_bounds__(512) void lstm_fused_kernel(
    const float* __restrict__ pre1p,
    const u16* __restrict__ w1p,
    const u16* __restrict__ w2ip, const u16* __restrict__ w2hp,
    const u16* b2ih, const u16* b2bhh,
    const u16* fc_w, const u16* fc_b, const int* flag,
    u32* ring, u32* flags, void* outv)
{
    const int tid = threadIdx.x;
    const int wave = tid>>6, lane = tid&63;
    const int l15 = lane&15, quad = lane>>4;
    const f32x4 fz = {0.f,0.f,0.f,0.f};

    if (blockIdx.x == 0) {
        // ================= producer: lstm1 =================
        __shared__ __align__(16) float pre_c[32*512];   // 64 KB
        __shared__ __align__(16) u16 hb1[2][128];
        __shared__ __align__(16) u16 hchunk[16*128];    // 4 KB
        const float4* p4g = (const float4*)pre1p;
        float4* c4 = (float4*)pre_c;
        u32* hc32 = (u32*)hchunk;

        short8 af1[4][4];
        #pragma unroll
        for (int i=0;i<4;i++)
            #pragma unroll
            for (int c=0;c<4;c++)
                af1[i][c] = *(const short8*)&w1p[(size_t)(wave*64 + i*16 + l15)*128 + c*32 + quad*8];

        const int uu = wave*16 + ((l15<4)?l15:0)*4 + quad;   // valid when l15<4
        const int pfo = uu*4;                                 // float offset in pre_c row
        float cst = 0.f;
        if (tid<128) hb1[1][tid]=0;

        // hoisted double-buffer read bases
        const u16* hqA = &hb1[1][quad*8];   // used when k even ((k+1)&1 == 1)
        const u16* hqB = &hb1[0][quad*8];
        const float* pcp = pre_c;           // rolling; reset each chunk

        for (int k=0;k<=1024;k++){
            if (k>=16 && (k&15)==0){
                int c = (k>>4) - 1;
                u32* dst = ring + c*1024;
                __hip_atomic_store(&dst[tid],     hc32[tid],     __ATOMIC_RELAXED, __HIP_MEMORY_SCOPE_AGENT);
                __hip_atomic_store(&dst[tid+512], hc32[tid+512], __ATOMIC_RELAXED, __HIP_MEMORY_SCOPE_AGENT);
                __syncthreads();   // drains vmcnt -> data stores complete
                if (tid==0)
                    __hip_atomic_store(&flags[c], (u32)(c+1), __ATOMIC_RELEASE, __HIP_MEMORY_SCOPE_AGENT);
            }
            if (k<1024 && (k&31)==0){
                #pragma unroll
                for (int j=0;j<8;j++) c4[j*512+tid] = p4g[(size_t)k*128 + j*512 + tid];
                pcp = pre_c;
                __syncthreads();
            }
            if (k<1024){
                const u16* hq = (k&1) ? hqB : hqA;
                short8 b0 = *(const short8*)&hq[0];
                short8 b1 = *(const short8*)&hq[32];
                short8 b2 = *(const short8*)&hq[64];
                short8 b3 = *(const short8*)&hq[96];
                f32x4 acc[4];
                #pragma unroll
                for (int i=0;i<4;i++){
                    f32x4 a = __builtin_amdgcn_mfma_f32_16x16x32_bf16(af1[i][0], b0, fz, 0,0,0);
                    a = __builtin_amdgcn_mfma_f32_16x16x32_bf16(af1[i][1], b1, a, 0,0,0);
                    a = __builtin_amdgcn_mfma_f32_16x16x32_bf16(af1[i][2], b2, a, 0,0,0);
                    a = __builtin_amdgcn_mfma_f32_16x16x32_bf16(af1[i][3], b3, a, 0,0,0);
                    acc[i] = a;
                }
                f32x4 z = acc[0];
                #pragma unroll
                for (int i=1;i<4;i++) z = (l15==i) ? acc[i] : z;
                if (l15<4){
                    const float4 pf = *(const float4*)&pcp[pfo];   // bias pre-folded
                    float zi = z[0]+pf.x;
                    float zf = z[1]+pf.y;
                    float zg = z[2]+pf.z;
                    float zo = z[3]+pf.w;
                    cst = sigm(zf)*cst + sigm(zi)*tanh_(zg);
                    float ho = sigm(zo)*tanh_(cst);
                    u16 hv = f2b(ho);
                    hb1[k&1][uu] = hv;
                    hchunk[(k&15)*128 + uu] = hv;
                }
                pcp += 512;
            }
            __syncthreads();
        }
    } else {
        // ================= consumer: lstm2 + FC =================
        __shared__ __align__(16) u16 h1c[16*136];       // padded rows
        __shared__ __align__(16) float z2l[16*264];     // padded rows
        __shared__ __align__(16) u16 hb2[2][64];
        __shared__ float hf[64];

        short8 af2[2][2];
        #pragma unroll
        for (int j=0;j<2;j++)
            #pragma unroll
            for (int c=0;c<2;c++)
                af2[j][c] = *(const short8*)&w2hp[(size_t)(wave*32 + j*16 + l15)*64 + c*32 + quad*8];
        short8 af3[2][4];
        #pragma unroll
        for (int j=0;j<2;j++)
            #pragma unroll
            for (int c=0;c<4;c++)
                af3[j][c] = *(const short8*)&w2ip[(size_t)(wave*32 + j*16 + l15)*128 + c*32 + quad*8];

        int u2 = 0; float bz0=0,bz1=0,bz2=0,bz3=0;
        if (l15<2){
            u2 = wave*8 + l15*4 + quad;
            bz0 = b2f(b2ih[u2])     + b2f(b2bhh[u2]);
            bz1 = b2f(b2ih[64+u2])  + b2f(b2bhh[64+u2]);
            bz2 = b2f(b2ih[128+u2]) + b2f(b2bhh[128+u2]);
            bz3 = b2f(b2ih[192+u2]) + b2f(b2bhh[192+u2]);
        }
        float cst = 0.f;
        if (tid<64) hb2[1][tid]=0;
        __syncthreads();

        u32* h1c32 = (u32*)h1c;
        for (int c=0;c<64;c++){
            if (tid==0){
                while (__hip_atomic_load(&flags[c], __ATOMIC_ACQUIRE, __HIP_MEMORY_SCOPE_AGENT) != (u32)(c+1))
                    __builtin_amdgcn_s_sleep(2);
            }
            __syncthreads();
            const u32* src = ring + c*1024;
            #pragma unroll
            for (int j=0;j<2;j++){
                int i = tid + j*512;
                u32 v = __hip_atomic_load(&src[i], __ATOMIC_RELAXED, __HIP_MEMORY_SCOPE_AGENT);
                int s = i>>6, w2 = i&63;
                h1c32[s*68 + w2] = v;
            }
            __syncthreads();
            short8 hbv[4];
            #pragma unroll
            for (int cc=0;cc<4;cc++)
                hbv[cc] = *(const short8*)&h1c[l15*136 + cc*32 + quad*8];
            f32x4 ba[2] = {fz,fz};
            #pragma unroll
            for (int cc=0;cc<4;cc++){
                ba[0] = __builtin_amdgcn_mfma_f32_16x16x32_bf16(af3[0][cc], hbv[cc], ba[0], 0,0,0);
                ba[1] = __builtin_amdgcn_mfma_f32_16x16x32_bf16(af3[1][cc], hbv[cc], ba[1], 0,0,0);
            }
            *(f32x4*)&z2l[l15*264 + (wave*8 + quad)*4]     = ba[0];
            *(f32x4*)&z2l[l15*264 + (wave*8 + 4 + quad)*4] = ba[1];
            __syncthreads();
            for (int s=0;s<16;s++){
                int sg = c*16 + s;
                const u16* hp2 = hb2[(sg+1)&1];
                short8 g0 = *(const short8*)&hp2[quad*8];
                short8 g1 = *(const short8*)&hp2[32+quad*8];
                f32x4 a0 = __builtin_amdgcn_mfma_f32_16x16x32_bf16(af2[0][0], g0, fz, 0,0,0);
                a0 = __builtin_amdgcn_mfma_f32_16x16x32_bf16(af2[0][1], g1, a0, 0,0,0);
                f32x4 a1 = __builtin_amdgcn_mfma_f32_16x16x32_bf16(af2[1][0], g0, fz, 0,0,0);
                a1 = __builtin_amdgcn_mfma_f32_16x16x32_bf16(af2[1][1], g1, a1, 0,0,0);
                f32x4 z = (l15==1) ? a1 : a0;
                if (l15<2){
                    const float4 pf = *(const float4*)&z2l[s*264 + u2*4];
                    float zi = z[0]+pf.x+bz0;
                    float zf = z[1]+pf.y+bz1;
                    float zg = z[2]+pf.z+bz2;
                    float zo = z[3]+pf.w+bz3;
                    cst = sigm(zf)*cst + sigm(zi)*tanh_(zg);
                    float ho = sigm(zo)*tanh_(cst);
                    hb2[sg&1][u2] = f2b(ho);
                    hf[u2] = ho;
                }
                __syncthreads();
            }
        }
        if (tid<4){
            float acc = b2f(fc_b[tid]);
            #pragma unroll
            for (int j=0;j<64;j++) acc += hf[j]*b2f(fc_w[tid*64+j]);
            if (*flag) ((float*)outv)[tid] = acc;
            else       ((u16*)outv)[tid]  = f2b(acc);
        }
    }
}

// ---------------------------------------------------------------------------
extern "C" void kernel_launch(void* const* d_in, const int* in_sizes, int n_in,
                              void* d_out, int out_size, void* d_ws, size_t ws_size,
                              hipStream_t stream) {
    const int* ei = (const int*)d_in[1];
    char* ws = (char*)d_ws;

    const size_t o_blob = 0;
    const size_t o_h    = 18733184;
    const size_t o_C    = o_h    + 34603008;
    const size_t o_wlrt = o_C    + 69206016;
    const size_t o_ep1  = o_wlrt + 1048576;
    const size_t o_ep2  = o_ep1  + 198656;
    const size_t o_csr  = o_ep2  + 198656;
    const size_t o_pre1 = o_csr  + 2048;
    const size_t o_w1p  = o_pre1 + 2097152;
    const size_t o_w2ip = o_w1p  + 131072;
    const size_t o_w2hp = o_w2ip + 65536;
    const size_t o_ring = o_w2hp + 32768;     // 64 chunks x 4096 B
    const size_t o_flgs = o_ring + 262144;

    u16*   blob  = (u16*)(ws + o_blob);
    u16*   h_buf = (u16*)(ws + o_h);
    u16*   Cbuf  = (u16*)(ws + o_C);
    u16*   wlrt  = (u16*)(ws + o_wlrt);
    float* ep1   = (float*)(ws + o_ep1);
    float* ep2   = (float*)(ws + o_ep2);
    int*   csr   = (int*)(ws + o_csr);
    int*   flag  = csr + 400;
    float* pre1  = (float*)(ws + o_pre1);
    u16*   w1p   = (u16*)(ws + o_w1p);
    u16*   w2ip  = (u16*)(ws + o_w2ip);
    u16*   w2hp  = (u16*)(ws + o_w2hp);
    u32*   ring  = (u32*)(ws + o_ring);
    u32*   flags = (u32*)(ws + o_flgs);
    float* part  = (float*)(ws + o_C);

    ConvArgs ca;
    const int blob_off[22] = {CX,CEA,CG1WL,CG1WR,CG1WE,CG1ATT,CG1B,
                              CG2WL,CG2WR,CG2WE,CG2ATT,CG2B,
                              CL1WIH,CL1WHH,CL1BIH,CL1BHH,
                              CL2WIH,CL2WHH,CL2BIH,CL2BHH,CFCW,CFCB};
    const int in_idx[22]   = {0,2,3,4,5,6,7,8,9,10,11,12,13,14,15,16,17,18,19,20,21,22};
    for (int s=0;s<22;s++){
        ca.src[s]=d_in[in_idx[s]]; ca.n[s]=in_sizes[in_idx[s]]; ca.off[s]=blob_off[s];
    }
    convert_kernel<<<2048,256,0,stream>>>(ca, (const u32*)d_in[3], flag, blob);

    prep_kernel<<<1089,256,0,stream>>>(ei, blob+CEA, blob+CG1WE, blob+CG2WE,
                                       blob+CG2WL, blob+CG2WR,
                                       blob+CL1WHH, blob+CL2WIH, blob+CL2WHH,
                                       csr, ep1, ep2, wlrt, w1p, w2ip, w2hp);
    gat1_kernel<<<NT,256,0,stream>>>(blob+CX, blob+CG1WL, blob+CG1WR, blob+CG1ATT,
                                     blob+CG1B, ep1, csr, h_buf);
    gemm_nt<<<dim3(8,264,1),256,0,stream>>>(h_buf, wlrt, Cbuf, 33792, 1024, 512, 512, 0);
    gat2_kernel<<<NT,256,0,stream>>>(Cbuf, blob+CG2ATT, blob+CG2B, ep2, csr, h_buf);
    gemm_nt<<<dim3(4,8,8),256,0,stream>>>(h_buf, blob+CL1WIH, part, 1024, 512, 16896, 2112, 1);
    reduce8_kernel<<<2048,256,0,stream>>>(part, blob+CL1BIH, blob+CL1BHH, pre1);
    lstm_fused_kernel<<<2,512,0,stream>>>(pre1,
        w1p, w2ip, w2hp, blob+CL2BIH, blob+CL2BHH,
        blob+CFCW, blob+CFCB, flag, ring, flags, d_out);
}